// Round 7
// baseline (448.068 us; speedup 1.0000x reference)
//
#include <hip/hip_runtime.h>

// DiffeomorphicLearnerTorch, R7: micro-block pipeline (3-wave barrier domain).
// Per step: Z += DT*(Z@Aaff^T + b + [ei*ej*exp(2*C1*Z@Z^T)]@A_t)
// R4/R5/R6 all plateaued at ~40us/k_flash despite 3 different memory
// arrangements => bottleneck is the 8-wave barrier lockstep, not loads.
// R7: block = 192 thr = 3 waves (1 producer + 2 consumers), 24KB LDS,
// <=128 VGPR -> 5 blocks/CU = 5 independent pipelines, barrier scope 3 waves.
// Frag-linear layouts (verified R4-R6):
//   Zf  [128 jblk][16 ks][64 lane]x8 bf16
//   ATf [t][8 dblk][256 jb][64 lane]x8 bf16

#define N_PTS 4096
#define DIM   256
#define DT_C  0.125f
#define C1    (1.0f/512.0f)

typedef __bf16 bf16x8 __attribute__((ext_vector_type(8)));
typedef float  f32x16 __attribute__((ext_vector_type(16)));
typedef float  f32x4v __attribute__((ext_vector_type(4)));
typedef unsigned int   u32x4 __attribute__((ext_vector_type(4)));
typedef unsigned short u16x8 __attribute__((ext_vector_type(8)));

__device__ __forceinline__ unsigned short f2bf(float f) {
  unsigned int u = __builtin_bit_cast(unsigned int, f);
  u += 0x7fffu + ((u >> 16) & 1u);          // RNE
  return (unsigned short)(u >> 16);
}
__device__ __forceinline__ float bf2f(unsigned short s) {
  unsigned int u = ((unsigned int)s) << 16;
  return __builtin_bit_cast(float, u);
}

// ---- ATf: A[t][4096][256] f32 -> frag-linear bf16 B-operand tiles ----
__global__ __launch_bounds__(256) void k_prep(const float* __restrict__ A,
                                              unsigned short* __restrict__ ATf) {
  __shared__ float sT[64][36];
  const int jgrp = blockIdx.x, ds = blockIdx.y, t = blockIdx.z;
  const int tid = threadIdx.x;
  const float* Ab = A + (size_t)t * N_PTS * DIM;
  {
    const int j_l = tid >> 2, dq = tid & 3;
    const float* src = Ab + (size_t)(jgrp * 64 + j_l) * DIM + ds * 32 + dq * 8;
    f32x4v v0 = *(const f32x4v*)src, v1 = *(const f32x4v*)(src + 4);
    *(f32x4v*)&sT[j_l][dq * 8] = v0;
    *(f32x4v*)&sT[j_l][dq * 8 + 4] = v1;
  }
  __syncthreads();
  const int jb_l = tid >> 6, l = tid & 63, l31 = l & 31, lhi = l >> 5;
  u16x8 o;
#pragma unroll
  for (int e = 0; e < 8; ++e) o[e] = f2bf(sT[jb_l * 16 + lhi * 8 + e][l31]);
  unsigned short* dst = ATf + (size_t)t * (8 * 256 * 64 * 8)
                      + ((size_t)(ds * 256 + jgrp * 4 + jb_l) * 64 + l) * 8;
  *(u16x8*)dst = o;
}

// ---- init: X -> Zf frags + erow ----
__global__ __launch_bounds__(256) void k_init(const float* __restrict__ X,
                                              unsigned short* __restrict__ Zf,
                                              float* __restrict__ erow) {
  const int tid = threadIdx.x;
  const int r = blockIdx.x * 8 + (tid >> 5), o = tid & 31;
  const size_t base = (size_t)r * DIM + o * 8;
  f32x4v z0 = *(const f32x4v*)(X + base), z1 = *(const f32x4v*)(X + base + 4);
  u16x8 zb; float s = 0.f;
#pragma unroll
  for (int i = 0; i < 4; ++i) { zb[i] = f2bf(z0[i]); zb[4 + i] = f2bf(z1[i]);
                                s += z0[i] * z0[i] + z1[i] * z1[i]; }
  *(u16x8*)(Zf + ((size_t)((r >> 5) * 16 + (o >> 1)) * 64 + (o & 1) * 32 + (r & 31)) * 8) = zb;
#pragma unroll
  for (int d = 16; d > 0; d >>= 1) s += __shfl_down(s, d, 32);
  if (o == 0) erow[r] = __expf(-s * C1);
}

// ---- fused flash, micro-block ----
// grid (8 chunks, 128 i-blocks of 32 rows), 192 thr = 3 waves.
// wave 0 producer: S = Zi(32) @ Zj(64)^T per tile (2 j-subs), P -> sP[n&1].
// waves 1,2 consumer cd: O(32i x 128d) += P @ A_t (b direct global);
//   + affine slice ksg=chunk*2+{0,1} (a-frags from sZi) during tile 0.
__global__ __launch_bounds__(192, 4) void k_flash(
    const unsigned short* __restrict__ Zf, const float* __restrict__ erow,
    const unsigned short* __restrict__ ATf_t,
    const float* __restrict__ Aaff_t,
    unsigned short* __restrict__ Opart) {
  __shared__ __align__(16) unsigned short sZi[16 * 64 * 8];  // 16KB frag-linear
  __shared__ __align__(16) unsigned short sP[2][32 * 64];    // 2 x 4KB swizzled

  const int tid = threadIdx.x, lane = tid & 63, wid = tid >> 6;
  const int l31 = lane & 31, lhi = lane >> 5;
  const int chunk = blockIdx.x;
  const int iblk = blockIdx.y;          // i-block of 32 rows
  const int i0 = iblk * 32;

  // stage sZi: 16KB contiguous slice of Zf (frag-linear already)
  {
    const unsigned short* src = Zf + (size_t)iblk * 8192;
#pragma unroll
    for (int p = 0; p < 6; ++p) {
      int idx = p * 192 + tid;
      if (idx < 1024)
        *(u32x4*)(sZi + (size_t)idx * 8) = *(const u32x4*)(src + (size_t)idx * 8);
    }
  }
  __syncthreads();

  if (wid == 0) {
    // ================= producer =================
    float eI[16];
#pragma unroll
    for (int c = 0; c < 16; ++c)
      eI[c] = erow[i0 + 4 * lhi + (c & 3) + 8 * (c >> 2)];

    for (int n = 0; n < 8; ++n) {
      unsigned short* pb = sP[n & 1];
#pragma unroll
      for (int jh = 0; jh < 2; ++jh) {
        // hoist all 16 b-frags for this j-sub (MLP=16)
        u32x4 bv[16];
        {
          const unsigned short* bp =
              Zf + ((size_t)(chunk * 16 + n * 2 + jh) * 16 * 64 + lane) * 8;
#pragma unroll
          for (int ks = 0; ks < 16; ++ks) bv[ks] = *(const u32x4*)(bp + ks * 512);
        }
        f32x16 S;
#pragma unroll
        for (int i = 0; i < 16; ++i) S[i] = 0.f;
#pragma unroll
        for (int ks = 0; ks < 16; ++ks) {
          bf16x8 af = *(const bf16x8*)(sZi + ((size_t)ks * 64 + lane) * 8);
          S = __builtin_amdgcn_mfma_f32_32x32x16_bf16(
              af, __builtin_bit_cast(bf16x8, bv[ks]), S, 0, 0, 0);
        }
        const float ej = erow[chunk * 512 + n * 64 + jh * 32 + l31];
        const int blk = jh * 4 + (l31 >> 3), cl = l31 & 7;
#pragma unroll
        for (int c = 0; c < 16; ++c) {
          const int row = 4 * lhi + (c & 3) + 8 * (c >> 2);
          pb[row * 64 + ((blk ^ (row & 7)) * 8) + cl] =
              f2bf(eI[c] * ej * __expf(2.f * C1 * S[c]));
        }
      }
      __syncthreads();
    }
    __syncthreads();   // match consumer's 9th barrier
  } else {
    // ================= consumer =================
    const int cd = wid - 1;   // d-half: d = cd*128 .. +128 (4 dblks of 32)
    f32x16 O[4];
#pragma unroll
    for (int ct = 0; ct < 4; ++ct)
#pragma unroll
      for (int i = 0; i < 16; ++i) O[ct][i] = 0.f;

    // affine slice (unscaled): ksg = chunk*2 + {0,1}; a-frags from sZi
#pragma unroll
    for (int q = 0; q < 2; ++q) {
      const int ksg = chunk * 2 + q;
      bf16x8 a = *(const bf16x8*)(sZi + ((size_t)ksg * 64 + lane) * 8);
#pragma unroll
      for (int ct = 0; ct < 4; ++ct) {
        const int d = (cd * 4 + ct) * 32 + l31;
        const float* bp = Aaff_t + (size_t)d * DIM + ksg * 16 + lhi * 8;
        f32x4v f0 = *(const f32x4v*)bp, f1 = *(const f32x4v*)(bp + 4);
        u16x8 tb;
#pragma unroll
        for (int i = 0; i < 4; ++i) { tb[i] = f2bf(f0[i]); tb[4 + i] = f2bf(f1[i]); }
        O[ct] = __builtin_amdgcn_mfma_f32_32x32x16_bf16(
            a, __builtin_bit_cast(bf16x8, tb), O[ct], 0, 0, 0);
      }
    }
    __syncthreads();   // barrier 1 (producer finished tile 0)

    for (int n = 1; n <= 8; ++n) {
      const int m = n - 1;
      const unsigned short* pb = sP[m & 1];
#pragma unroll
      for (int ksp = 0; ksp < 2; ++ksp) {
        // hoist 8 ATf b-frags (2 ks x 4 dblk, MLP=8)
        u32x4 bw[8];
#pragma unroll
        for (int k2 = 0; k2 < 2; ++k2)
#pragma unroll
          for (int ct = 0; ct < 4; ++ct)
            bw[k2 * 4 + ct] = *(const u32x4*)(ATf_t +
                ((size_t)((cd * 4 + ct) * 256 + chunk * 32 + m * 4 + ksp * 2 + k2) * 64 + lane) * 8);
#pragma unroll
        for (int k2 = 0; k2 < 2; ++k2) {
          const int ks = ksp * 2 + k2;
          const int blk = ks * 2 + lhi;
          const int row = l31;
          bf16x8 a = *(const bf16x8*)&pb[row * 64 + ((blk ^ (row & 7)) * 8)];
#pragma unroll
          for (int ct = 0; ct < 4; ++ct)
            O[ct] = __builtin_amdgcn_mfma_f32_32x32x16_bf16(
                a, __builtin_bit_cast(bf16x8, bw[k2 * 4 + ct]), O[ct], 0, 0, 0);
        }
      }
      __syncthreads();
    }

    // epilogue -> Opart[chunk] bf16 (P already carries ei*ej)
    unsigned short* ob = Opart + (size_t)chunk * N_PTS * DIM + (size_t)cd * 128 + l31;
#pragma unroll
    for (int ct = 0; ct < 4; ++ct)
#pragma unroll
      for (int c = 0; c < 16; ++c) {
        const int row = i0 + 4 * lhi + (c & 3) + 8 * (c >> 2);
        ob[(size_t)row * DIM + ct * 32] = f2bf(O[ct][c]);
      }
  }
}

// ---- update: Z += DT*(sum partials + baff); emit Zf frags + erow ----
__global__ __launch_bounds__(256) void k_update(const float* __restrict__ Zin,
                                                const unsigned short* __restrict__ Opart,
                                                const float* __restrict__ baff_t,
                                                float* __restrict__ Zout,
                                                unsigned short* __restrict__ Zf,
                                                float* __restrict__ erow) {
  const int tid = threadIdx.x;
  const int r = blockIdx.x * 8 + (tid >> 5), o = tid & 31;
  const size_t base = (size_t)r * DIM + o * 8;
  f32x4v z0 = *(const f32x4v*)(Zin + base), z1 = *(const f32x4v*)(Zin + base + 4);
  f32x4v s0 = *(const f32x4v*)(baff_t + o * 8), s1 = *(const f32x4v*)(baff_t + o * 8 + 4);
#pragma unroll
  for (int c = 0; c < 8; ++c) {
    u16x8 p = *(const u16x8*)(Opart + (size_t)c * N_PTS * DIM + base);
#pragma unroll
    for (int i = 0; i < 4; ++i) { s0[i] += bf2f(p[i]); s1[i] += bf2f(p[4 + i]); }
  }
  u16x8 zb; float sv = 0.f;
#pragma unroll
  for (int i = 0; i < 4; ++i) {
    z0[i] += DT_C * s0[i]; z1[i] += DT_C * s1[i];
    zb[i] = f2bf(z0[i]); zb[4 + i] = f2bf(z1[i]);
    sv += z0[i] * z0[i] + z1[i] * z1[i];
  }
  *(f32x4v*)(Zout + base) = z0;
  *(f32x4v*)(Zout + base + 4) = z1;
  *(u16x8*)(Zf + ((size_t)((r >> 5) * 16 + (o >> 1)) * 64 + (o & 1) * 32 + (r & 31)) * 8) = zb;
#pragma unroll
  for (int d = 16; d > 0; d >>= 1) sv += __shfl_down(sv, d, 32);
  if (o == 0) erow[r] = __expf(-sv * C1);
}

extern "C" void kernel_launch(void* const* d_in, const int* in_sizes, int n_in,
                              void* d_out, int out_size, void* d_ws, size_t ws_size,
                              hipStream_t stream) {
  const float* X    = (const float*)d_in[0];
  const float* A    = (const float*)d_in[1];
  const float* Aaff = (const float*)d_in[2];
  const float* baff = (const float*)d_in[3];
  float* out = (float*)d_out;

  char* w = (char*)d_ws;
  size_t off = 0;
  unsigned short* ATf = (unsigned short*)(w + off); off += (size_t)8 * 8 * 256 * 64 * 8 * 2; // 16 MiB
  unsigned short* Zf  = (unsigned short*)(w + off); off += (size_t)N_PTS * DIM * 2;          // 2 MiB
  float* erow = (float*)(w + off); off += (size_t)N_PTS * 4;
  float* Zf32 = (float*)(w + off); off += (size_t)N_PTS * DIM * 4;                           // 4 MiB
  unsigned short* Opart = (unsigned short*)(w + off); off += (size_t)8 * N_PTS * DIM * 2;    // 16 MiB
  (void)ws_size; (void)in_sizes; (void)n_in; (void)out_size;

  k_prep<<<dim3(64, 8, 8), 256, 0, stream>>>(A, ATf);
  k_init<<<512, 256, 0, stream>>>(X, Zf, erow);

  const float* zin = X;
  for (int t = 0; t < 8; ++t) {
    float* zout = (t == 7) ? out : Zf32;  // in-place safe after t=0
    k_flash<<<dim3(8, 128), 192, 0, stream>>>(
        Zf, erow, ATf + (size_t)t * (8 * 256 * 64 * 8), Aaff + (size_t)t * DIM * DIM, Opart);
    k_update<<<512, 256, 0, stream>>>(zin, Opart, baff + (size_t)t * DIM, zout, Zf, erow);
    zin = zout;
  }
}